// Round 1
// baseline (1702.588 us; speedup 1.0000x reference)
//
#include <hip/hip_runtime.h>

// KAN FFN on MI355X: each KAN linear = one bf16 GEMM over concatenated
// [silu(x) | b-spline bases] activation (K = 9*d_in) against
// [base_w | spline_w*scaler] weights, fp32 accumulate.
//
// ws layout (218.1 MB total):
//   regionA (75.5MB): W1aug  -> reused as Act2 K-chunk buffers
//   regionB (75.5MB): Act1   -> reused as W2aug
//   regionC (67.1MB): h (fp32 intermediate, 4096x4096)

typedef unsigned short u16;
typedef __bf16 bf16x8 __attribute__((ext_vector_type(8)));
typedef float f32x4 __attribute__((ext_vector_type(4)));
typedef u16 u16x8 __attribute__((ext_vector_type(8)));

#define D_MODEL 1024
#define D_FF    4096
#define NTOK    4096
#define K1      9216    // 9*1024
#define K2      36864   // 9*4096
#define KCHUNK  9216    // K2 / 4

__device__ __forceinline__ u16 f2bf(float v) {
    union { float f; unsigned u; } a; a.f = v;
    unsigned r = a.u + 0x7FFFu + ((a.u >> 16) & 1u);  // RNE
    return (u16)(r >> 16);
}

__device__ __forceinline__ float silu_f(float x) {
    return x / (1.f + __expf(-x));
}

__device__ __forceinline__ void llds16(const u16* g, u16* l) {
    __builtin_amdgcn_global_load_lds(
        (__attribute__((address_space(1))) void*)(u16*)g,
        (__attribute__((address_space(3))) void*)l,
        16, 0, 0);
}

// ---------------------------------------------------------------------------
// Build augmented weight matrix: dst[o][i] = bf16(base_w[o][i]) for i<IN,
// dst[o][IN + 8*i + c] = bf16(spline_w[o][i][c] * scaler[o][i]).
__global__ __launch_bounds__(256) void build_w(
    const float* __restrict__ bw, const float* __restrict__ sw,
    const float* __restrict__ sc, u16* __restrict__ dst,
    int IN, int shift)
{
    const int idx = blockIdx.x * 256 + threadIdx.x;      // o*IN + i
    const int o = idx >> shift;
    const int i = idx & (IN - 1);
    const int rowLen = IN * 9;
    const float scv = sc[idx];
    const float* sp = sw + (size_t)idx * 8;
    f32x4 s0 = *(const f32x4*)sp;
    f32x4 s1 = *(const f32x4*)(sp + 4);
    u16x8 p;
#pragma unroll
    for (int t = 0; t < 4; ++t) {
        p[t]     = f2bf(s0[t] * scv);
        p[t + 4] = f2bf(s1[t] * scv);
    }
    dst[(size_t)o * rowLen + i] = f2bf(bw[idx]);
    *(u16x8*)(dst + (size_t)o * rowLen + IN + (size_t)i * 8) = p;
}

// ---------------------------------------------------------------------------
// Build a 9216-column chunk of the augmented activation matrix from fp32 src.
// Column (col0+g*8+t): silu(src[n][col]) if col < srcCols, else b-spline
// basis c=(col-srcCols)&7 of src[n][(col-srcCols)>>3].
// grid (9, 4096), block 128  -> g in [0,1152), 8 cols per thread.
__global__ __launch_bounds__(128) void build_act(
    const float* __restrict__ src, int srcCols,
    u16* __restrict__ dst, int col0)
{
    const int g = blockIdx.x * 128 + threadIdx.x;        // group of 8 cols
    const int n = blockIdx.y;
    const int base = col0 + g * 8;
    u16x8 p;
    if (base < srcCols) {
        const float* sp = src + (size_t)n * srcCols + base;
        f32x4 v0 = *(const f32x4*)sp;
        f32x4 v1 = *(const f32x4*)(sp + 4);
#pragma unroll
        for (int t = 0; t < 4; ++t) {
            p[t]     = f2bf(silu_f(v0[t]));
            p[t + 4] = f2bf(silu_f(v1[t]));
        }
    } else {
        const int i = (base - srcCols) >> 3;
        const float xv = src[(size_t)n * srcCols + i];
        // t in knot units from g[0]=-2.2, spacing h=0.4
        const float t = (xv + 2.2f) * 2.5f;
        const bool inr = (t >= 0.f) && (t < 11.f);
        const float jf = floorf(t);
        const int j = (int)jf;
        const float f = t - jf;
        const float f2 = f * f, f3 = f2 * f;
        const float s6 = 1.f / 6.f;
        const float w3 = f3 * s6;                              // c = j
        const float w2 = (1.f + 3.f*f + 3.f*f2 - 3.f*f3) * s6; // c = j-1
        const float w1 = (4.f - 6.f*f2 + 3.f*f3) * s6;         // c = j-2
        float w0 = 1.f - f; w0 = w0 * w0 * w0 * s6;            // c = j-3
#pragma unroll
        for (int c = 0; c < 8; ++c) {
            float v = 0.f;
            v = (j == c)     ? w3 : v;
            v = (j == c + 1) ? w2 : v;
            v = (j == c + 2) ? w1 : v;
            v = (j == c + 3) ? w0 : v;
            v = inr ? v : 0.f;
            p[c] = f2bf(v);
        }
    }
    *(u16x8*)(dst + (size_t)n * 9216 + (size_t)g * 8) = p;
}

// ---------------------------------------------------------------------------
// C[M,N] (+)= A[M,K] * B[N,K]^T   (bf16 in, fp32 out)
// m97 structure: 2-barrier K-loop, global_load_lds width 16,
// 4 waves in 2x2, per-wave (BM/2)x(BN/2) via 16x16x32 MFMA frags.
template <int BM, int BN>
__global__ __launch_bounds__(256) void gemm_bt(
    const u16* __restrict__ A, int lda,
    const u16* __restrict__ B, int ldb,
    float* __restrict__ C, int ldc,
    int K, int accumulate)
{
    __shared__ __attribute__((aligned(16))) u16 As[BM * 64];
    __shared__ __attribute__((aligned(16))) u16 Bs[BN * 64];
    const int tid  = threadIdx.x;
    const int lane = tid & 63;
    const int wave = tid >> 6;
    const int wr = wave >> 1;
    const int wc = wave & 1;
    constexpr int MR = BM / 32;   // 16x16 frags per wave along M
    constexpr int NR = BN / 32;
    const int m0 = blockIdx.y * BM;
    const int n0 = blockIdx.x * BN;

    const f32x4 zero = {0.f, 0.f, 0.f, 0.f};
    f32x4 acc[MR][NR];
#pragma unroll
    for (int a = 0; a < MR; ++a)
#pragma unroll
        for (int b = 0; b < NR; ++b)
            acc[a][b] = zero;

    // staging: issue q covers rows [q*32, q*32+32) of the tile, 8 bf16/lane
    const int srow = tid >> 3;
    const int scol = (tid & 7) * 8;
    const u16* Ag = A + (size_t)(m0 + srow) * lda + scol;
    const u16* Bg = B + (size_t)(n0 + srow) * ldb + scol;
    u16* AsW = &As[wave * 512];
    u16* BsW = &Bs[wave * 512];

    const int arow = lane & 15;
    const int akk  = (lane >> 4) * 8;
    const int nk = K >> 6;

    for (int kt = 0; kt < nk; ++kt) {
        if (kt) __syncthreads();
        const int k0 = kt << 6;
#pragma unroll
        for (int q = 0; q < BM / 32; ++q)
            llds16(Ag + (size_t)q * 32 * lda + k0, AsW + q * 2048);
#pragma unroll
        for (int q = 0; q < BN / 32; ++q)
            llds16(Bg + (size_t)q * 32 * ldb + k0, BsW + q * 2048);
        __syncthreads();
#pragma unroll
        for (int kk = 0; kk < 64; kk += 32) {
            bf16x8 af[MR], bfr[NR];
#pragma unroll
            for (int mi = 0; mi < MR; ++mi)
                af[mi] = *(const bf16x8*)&As[(wr * (BM / 2) + mi * 16 + arow) * 64 + kk + akk];
#pragma unroll
            for (int ni = 0; ni < NR; ++ni)
                bfr[ni] = *(const bf16x8*)&Bs[(wc * (BN / 2) + ni * 16 + arow) * 64 + kk + akk];
#pragma unroll
            for (int mi = 0; mi < MR; ++mi)
#pragma unroll
                for (int ni = 0; ni < NR; ++ni)
                    acc[mi][ni] = __builtin_amdgcn_mfma_f32_16x16x32_bf16(
                        af[mi], bfr[ni], acc[mi][ni], 0, 0, 0);
        }
    }

    const int r0 = (lane >> 4) * 4;
    const int cn = lane & 15;
#pragma unroll
    for (int mi = 0; mi < MR; ++mi)
#pragma unroll
        for (int ni = 0; ni < NR; ++ni) {
#pragma unroll
            for (int j = 0; j < 4; ++j) {
                const int m = m0 + wr * (BM / 2) + mi * 16 + r0 + j;
                const int n = n0 + wc * (BN / 2) + ni * 16 + cn;
                const float v = acc[mi][ni][j];
                if (accumulate) C[(size_t)m * ldc + n] += v;
                else            C[(size_t)m * ldc + n] = v;
            }
        }
}

// ---------------------------------------------------------------------------
extern "C" void kernel_launch(void* const* d_in, const int* in_sizes, int n_in,
                              void* d_out, int out_size, void* d_ws, size_t ws_size,
                              hipStream_t stream) {
    const float* x   = (const float*)d_in[0];
    const float* bw1 = (const float*)d_in[1];
    const float* sw1 = (const float*)d_in[2];
    const float* sc1 = (const float*)d_in[3];
    const float* bw2 = (const float*)d_in[4];
    const float* sw2 = (const float*)d_in[5];
    const float* sc2 = (const float*)d_in[6];
    float* out = (float*)d_out;

    char* ws = (char*)d_ws;
    u16*   regionA = (u16*)ws;                            // 75,497,472 B
    u16*   regionB = (u16*)(ws + 75497472);               // 75,497,472 B
    float* hbuf    = (float*)(ws + 150994944);            // 67,108,864 B

    // ---- layer 1 ----
    build_w<<<16384, 256, 0, stream>>>(bw1, sw1, sc1, regionA, D_MODEL, 10);
    build_act<<<dim3(9, NTOK), 128, 0, stream>>>(x, D_MODEL, regionB, 0);
    gemm_bt<128, 128><<<dim3(32, 32), 256, 0, stream>>>(
        regionB, K1, regionA, K1, hbuf, D_FF, K1, 0);

    // ---- layer 2 (K chunked into 4 x 9216; Act chunk reuses regionA) ----
    build_w<<<16384, 256, 0, stream>>>(bw2, sw2, sc2, regionB, D_FF, 12);
    for (int ck = 0; ck < 4; ++ck) {
        build_act<<<dim3(9, NTOK), 128, 0, stream>>>(hbuf, D_FF, regionA, ck * KCHUNK);
        gemm_bt<128, 64><<<dim3(16, 32), 256, 0, stream>>>(
            regionA, KCHUNK, regionB + (size_t)ck * KCHUNK, K2,
            out, D_MODEL, KCHUNK, ck > 0 ? 1 : 0);
    }
}

// Round 2
// 1268.176 us; speedup vs baseline: 1.3425x; 1.3425x over previous
//
#include <hip/hip_runtime.h>

// KAN FFN on MI355X. Each KAN linear = one bf16 GEMM over concatenated
// [silu(x) | cubic b-spline bases] activation (K = 9*d_in) vs
// [base_w | spline_w*scaler], fp32 accumulate.
// GEMM: 256x256 tile, BK=64, 8 waves (2Mx4N), 4-phase/K-tile schedule with
// raw barriers, distance-1 double-buffered global_load_lds staging (boundary
// drain after 4 phases of MFMA overlap), XOR8 LDS swizzle (inverse-swizzled
// global source + swizzled ds_read), setprio around MFMA, XCD block swizzle.

typedef unsigned short u16;
typedef __bf16 bf16x8 __attribute__((ext_vector_type(8)));
typedef float f32x4 __attribute__((ext_vector_type(4)));
typedef u16 u16x8 __attribute__((ext_vector_type(8)));

#define D_MODEL 1024
#define D_FF    4096
#define NTOK    4096
#define K1      9216    // 9*1024
#define K2      36864   // 9*4096
#define KCHUNK  9216    // K2 / 4

__device__ __forceinline__ u16 f2bf(float v) {
    union { float f; unsigned u; } a; a.f = v;
    unsigned r = a.u + 0x7FFFu + ((a.u >> 16) & 1u);  // RNE
    return (u16)(r >> 16);
}

__device__ __forceinline__ float silu_f(float x) {
    return x / (1.f + __expf(-x));
}

__device__ __forceinline__ void llds16(const u16* g, u16* l) {
    __builtin_amdgcn_global_load_lds(
        (__attribute__((address_space(1))) void*)(u16*)g,
        (__attribute__((address_space(3))) void*)l,
        16, 0, 0);
}

// ---------------------------------------------------------------------------
__global__ __launch_bounds__(256) void build_w(
    const float* __restrict__ bw, const float* __restrict__ sw,
    const float* __restrict__ sc, u16* __restrict__ dst,
    int IN, int shift)
{
    const int idx = blockIdx.x * 256 + threadIdx.x;      // o*IN + i
    const int o = idx >> shift;
    const int i = idx & (IN - 1);
    const int rowLen = IN * 9;
    const float scv = sc[idx];
    const float* sp = sw + (size_t)idx * 8;
    f32x4 s0 = *(const f32x4*)sp;
    f32x4 s1 = *(const f32x4*)(sp + 4);
    u16x8 p;
#pragma unroll
    for (int t = 0; t < 4; ++t) {
        p[t]     = f2bf(s0[t] * scv);
        p[t + 4] = f2bf(s1[t] * scv);
    }
    dst[(size_t)o * rowLen + i] = f2bf(bw[idx]);
    *(u16x8*)(dst + (size_t)o * rowLen + IN + (size_t)i * 8) = p;
}

// ---------------------------------------------------------------------------
__global__ __launch_bounds__(128) void build_act(
    const float* __restrict__ src, int srcCols,
    u16* __restrict__ dst, int col0)
{
    const int g = blockIdx.x * 128 + threadIdx.x;        // group of 8 cols
    const int n = blockIdx.y;
    const int base = col0 + g * 8;
    u16x8 p;
    if (base < srcCols) {
        const float* sp = src + (size_t)n * srcCols + base;
        f32x4 v0 = *(const f32x4*)sp;
        f32x4 v1 = *(const f32x4*)(sp + 4);
#pragma unroll
        for (int t = 0; t < 4; ++t) {
            p[t]     = f2bf(silu_f(v0[t]));
            p[t + 4] = f2bf(silu_f(v1[t]));
        }
    } else {
        const int i = (base - srcCols) >> 3;
        const float xv = src[(size_t)n * srcCols + i];
        const float t = (xv + 2.2f) * 2.5f;               // knot units
        const bool inr = (t >= 0.f) && (t < 11.f);
        const float jf = floorf(t);
        const int j = (int)jf;
        const float f = t - jf;
        const float f2 = f * f, f3 = f2 * f;
        const float s6 = 1.f / 6.f;
        const float w3 = f3 * s6;
        const float w2 = (1.f + 3.f*f + 3.f*f2 - 3.f*f3) * s6;
        const float w1 = (4.f - 6.f*f2 + 3.f*f3) * s6;
        float w0 = 1.f - f; w0 = w0 * w0 * w0 * s6;
#pragma unroll
        for (int c = 0; c < 8; ++c) {
            float v = 0.f;
            v = (j == c)     ? w3 : v;
            v = (j == c + 1) ? w2 : v;
            v = (j == c + 2) ? w1 : v;
            v = (j == c + 3) ? w0 : v;
            v = inr ? v : 0.f;
            p[c] = f2bf(v);
        }
    }
    *(u16x8*)(dst + (size_t)n * 9216 + (size_t)g * 8) = p;
}

// ---------------------------------------------------------------------------
// C[M,N] = A[M,K]*B[N,K]^T (bf16 in, fp32 out). 256x256 tile, BK=64.
// Split-K via blockIdx.z (k0 = bz*nk*64); ATOMIC=1 -> atomicAdd into C.
template <int ATOMIC>
__global__ __launch_bounds__(512, 2) void gemm256(
    const u16* __restrict__ A, int lda,
    const u16* __restrict__ B, int ldb,
    float* __restrict__ C, int ldc,
    int nk)
{
    __shared__ __attribute__((aligned(16))) u16 sm[2][2][256][64];  // 128 KiB

    const int tid  = threadIdx.x;
    const int lane = tid & 63;
    const int wave = tid >> 6;
    const int wr = wave >> 2;          // 0..1
    const int wc = wave & 3;           // 0..3

    // XCD-aware bijective swizzle (all grids here have nwg % 8 == 0)
    const int gx = gridDim.x, gy = gridDim.y, gz = gridDim.z;
    int flat = (blockIdx.z * gy + blockIdx.y) * gx + blockIdx.x;
    const int nwg = gx * gy * gz;
    const int cpx = nwg >> 3;
    flat = (flat & 7) * cpx + (flat >> 3);
    const int bx = flat % gx;
    const int by = (flat / gx) % gy;
    const int bz = flat / (gx * gy);

    const int m0 = by * 256;
    const int n0 = bx * 256;
    const int k0 = bz * nk * 64;

    // staging: lane l covers row (chunk + l>>3), 16B unit ((l&7) ^ (l>>3))
    // (inverse XOR8 swizzle on the global source; LDS dest stays linear)
    const int sR = lane >> 3;
    const int sC = ((lane & 7) ^ sR) * 8;
    const u16* Ast = A + (size_t)(m0 + sR) * lda + k0 + sC;
    const u16* Bst = B + (size_t)(n0 + sR) * ldb + k0 + sC;

    // fragment reads: row R = base + (lane&15); swizzled col = c ^ ((R&7)<<3)
    const int fRow = lane & 15;
    const int cxor = (lane & 7) << 3;
    const int colK0 = (((lane >> 4) * 8) + 0 ) ^ cxor;
    const int colK1 = (((lane >> 4) * 8) + 32) ^ cxor;
    const int aRow = wr * 128 + fRow;
    const int bRow = wc * 64 + fRow;

    const f32x4 zero = {0.f, 0.f, 0.f, 0.f};
    f32x4 acc[8][4];
#pragma unroll
    for (int a = 0; a < 8; ++a)
#pragma unroll
        for (int b = 0; b < 4; ++b) acc[a][b] = zero;

    auto stage = [&](int bufSel, int ktile, int q) {
        const int sel  = q & 1;       // 0=A, 1=B  (order: A0,B0,A1,B1)
        const int half = q >> 1;
#pragma unroll
        for (int i = 0; i < 2; ++i) {
            const int r0 = half * 128 + wave * 16 + i * 8;
            if (sel == 0)
                llds16(Ast + (size_t)r0 * lda + (size_t)ktile * 64,
                       &sm[bufSel][0][r0][0]);
            else
                llds16(Bst + (size_t)r0 * ldb + (size_t)ktile * 64,
                       &sm[bufSel][1][r0][0]);
        }
    };

    // prologue: stage K-tile 0 fully into buf 0
#pragma unroll
    for (int q = 0; q < 4; ++q) stage(0, 0, q);
    asm volatile("s_waitcnt vmcnt(0)" ::: "memory");
    __builtin_amdgcn_s_barrier();
    __builtin_amdgcn_sched_barrier(0);

    for (int kt = 0; kt < nk; ++kt) {
        const int b = kt & 1;
        const bool st = (kt + 1 < nk);
        bf16x8 b0[4], b1[4];
#pragma unroll
        for (int q = 0; q < 4; ++q) {
            // ds-load this phase's register subtile (from buf b)
            bf16x8 a00 = *(const bf16x8*)&sm[b][0][aRow + q*32     ][colK0];
            bf16x8 a10 = *(const bf16x8*)&sm[b][0][aRow + q*32 + 16][colK0];
            bf16x8 a01 = *(const bf16x8*)&sm[b][0][aRow + q*32     ][colK1];
            bf16x8 a11 = *(const bf16x8*)&sm[b][0][aRow + q*32 + 16][colK1];
            if (q == 0) {
#pragma unroll
                for (int nf = 0; nf < 4; ++nf) {
                    b0[nf] = *(const bf16x8*)&sm[b][1][bRow + nf*16][colK0];
                    b1[nf] = *(const bf16x8*)&sm[b][1][bRow + nf*16][colK1];
                }
            }
            // stage one half-tile of K-tile kt+1 into buf b^1
            if (st) stage(b ^ 1, kt + 1, q);
            __builtin_amdgcn_s_barrier();
            asm volatile("s_waitcnt lgkmcnt(0)" ::: "memory");
            __builtin_amdgcn_sched_barrier(0);
            __builtin_amdgcn_s_setprio(1);
#pragma unroll
            for (int nf = 0; nf < 4; ++nf)
                acc[2*q  ][nf] = __builtin_amdgcn_mfma_f32_16x16x32_bf16(
                    a00, b0[nf], acc[2*q  ][nf], 0, 0, 0);
#pragma unroll
            for (int nf = 0; nf < 4; ++nf)
                acc[2*q+1][nf] = __builtin_amdgcn_mfma_f32_16x16x32_bf16(
                    a10, b0[nf], acc[2*q+1][nf], 0, 0, 0);
#pragma unroll
            for (int nf = 0; nf < 4; ++nf)
                acc[2*q  ][nf] = __builtin_amdgcn_mfma_f32_16x16x32_bf16(
                    a01, b1[nf], acc[2*q  ][nf], 0, 0, 0);
#pragma unroll
            for (int nf = 0; nf < 4; ++nf)
                acc[2*q+1][nf] = __builtin_amdgcn_mfma_f32_16x16x32_bf16(
                    a11, b1[nf], acc[2*q+1][nf], 0, 0, 0);
            __builtin_amdgcn_s_setprio(0);
            __builtin_amdgcn_sched_barrier(0);
            if (q == 3 && st)
                asm volatile("s_waitcnt vmcnt(0)" ::: "memory");
            __builtin_amdgcn_s_barrier();
            __builtin_amdgcn_sched_barrier(0);
        }
    }

    // epilogue
    const int cRow = m0 + wr * 128 + (lane >> 4) * 4;
    const int cCol = n0 + wc * 64 + (lane & 15);
#pragma unroll
    for (int af = 0; af < 8; ++af)
#pragma unroll
        for (int nf = 0; nf < 4; ++nf)
#pragma unroll
            for (int j = 0; j < 4; ++j) {
                const size_t off = (size_t)(cRow + af * 16 + j) * ldc
                                 + (cCol + nf * 16);
                if (ATOMIC) atomicAdd(&C[off], acc[af][nf][j]);
                else        C[off] = acc[af][nf][j];
            }
}

// ---------------------------------------------------------------------------
extern "C" void kernel_launch(void* const* d_in, const int* in_sizes, int n_in,
                              void* d_out, int out_size, void* d_ws, size_t ws_size,
                              hipStream_t stream) {
    const float* x   = (const float*)d_in[0];
    const float* bw1 = (const float*)d_in[1];
    const float* sw1 = (const float*)d_in[2];
    const float* sc1 = (const float*)d_in[3];
    const float* bw2 = (const float*)d_in[4];
    const float* sw2 = (const float*)d_in[5];
    const float* sc2 = (const float*)d_in[6];
    float* out = (float*)d_out;

    char* ws = (char*)d_ws;
    u16*   regionA = (u16*)ws;                            // 75,497,472 B
    u16*   regionB = (u16*)(ws + 75497472);               // 75,497,472 B
    float* hbuf    = (float*)(ws + 150994944);            // 67,108,864 B

    // zero output (layer-2 GEMM accumulates atomically)
    hipMemsetAsync(d_out, 0, (size_t)NTOK * D_MODEL * sizeof(float), stream);

    // ---- layer 1 ----
    build_w<<<16384, 256, 0, stream>>>(bw1, sw1, sc1, regionA, D_MODEL, 10);
    build_act<<<dim3(9, NTOK), 128, 0, stream>>>(x, D_MODEL, regionB, 0);
    gemm256<0><<<dim3(16, 16, 1), 512, 0, stream>>>(
        regionB, K1, regionA, K1, hbuf, D_FF, 144);

    // ---- layer 2: 4 K-chunks, each split-K z=4 (256 blocks/dispatch) ----
    build_w<<<16384, 256, 0, stream>>>(bw2, sw2, sc2, regionB, D_FF, 12);
    for (int ck = 0; ck < 4; ++ck) {
        build_act<<<dim3(9, NTOK), 128, 0, stream>>>(hbuf, D_FF, regionA, ck * KCHUNK);
        gemm256<1><<<dim3(4, 16, 4), 512, 0, stream>>>(
            regionA, KCHUNK, regionB + (size_t)ck * KCHUNK, K2,
            out, D_MODEL, 36);
    }
}

// Round 3
// 1050.000 us; speedup vs baseline: 1.6215x; 1.2078x over previous
//
#include <hip/hip_runtime.h>

// KAN FFN on MI355X. Each KAN linear = one bf16 GEMM over concatenated
// [silu(x) | cubic b-spline bases] activation (K = 9*d_in) vs
// [base_w | spline_w*scaler], fp32 accumulate.
//
// GEMM: 256x256 tile, BK=64 split in two K-halves, 8 waves (2Mx4N).
// 4 phases/K-tile; staging by K-half slabs [256][32] so counted vmcnt(4)
// (never 0 in the main loop) lets loads span tile boundaries (T3+T4).
// XOR swizzle u ^= (row>>1)&3 on 16B units (inverse-swizzled global source,
// swizzled ds_read). setprio around MFMA (T5), XCD block swizzle (T1).
// Layer 2: split-K z=4 into 4 fp32 partial buffers (no atomics) + reduce,
// falling back to atomicAdd if ws_size is too small.

typedef unsigned short u16;
typedef __bf16 bf16x8 __attribute__((ext_vector_type(8)));
typedef float f32x4 __attribute__((ext_vector_type(4)));
typedef u16 u16x8 __attribute__((ext_vector_type(8)));

#define D_MODEL 1024
#define D_FF    4096
#define NTOK    4096
#define K1      9216    // 9*1024
#define K2      36864   // 9*4096
#define KCHUNK  9216    // K2 / 4

__device__ __forceinline__ u16 f2bf(float v) {
    union { float f; unsigned u; } a; a.f = v;
    unsigned r = a.u + 0x7FFFu + ((a.u >> 16) & 1u);  // RNE
    return (u16)(r >> 16);
}

__device__ __forceinline__ float silu_f(float x) {
    return x / (1.f + __expf(-x));
}

__device__ __forceinline__ void llds16(const u16* g, u16* l) {
    __builtin_amdgcn_global_load_lds(
        (__attribute__((address_space(1))) void*)(u16*)g,
        (__attribute__((address_space(3))) void*)l,
        16, 0, 0);
}

// ---------------------------------------------------------------------------
__global__ __launch_bounds__(256) void build_w(
    const float* __restrict__ bw, const float* __restrict__ sw,
    const float* __restrict__ sc, u16* __restrict__ dst,
    int IN, int shift)
{
    const int idx = blockIdx.x * 256 + threadIdx.x;      // o*IN + i
    const int o = idx >> shift;
    const int i = idx & (IN - 1);
    const int rowLen = IN * 9;
    const float scv = sc[idx];
    const float* sp = sw + (size_t)idx * 8;
    f32x4 s0 = *(const f32x4*)sp;
    f32x4 s1 = *(const f32x4*)(sp + 4);
    u16x8 p;
#pragma unroll
    for (int t = 0; t < 4; ++t) {
        p[t]     = f2bf(s0[t] * scv);
        p[t + 4] = f2bf(s1[t] * scv);
    }
    dst[(size_t)o * rowLen + i] = f2bf(bw[idx]);
    *(u16x8*)(dst + (size_t)o * rowLen + IN + (size_t)i * 8) = p;
}

// ---------------------------------------------------------------------------
__global__ __launch_bounds__(128) void build_act(
    const float* __restrict__ src, int srcCols,
    u16* __restrict__ dst, int col0)
{
    const int g = blockIdx.x * 128 + threadIdx.x;        // group of 8 cols
    const int n = blockIdx.y;
    const int base = col0 + g * 8;
    u16x8 p;
    if (base < srcCols) {
        const float* sp = src + (size_t)n * srcCols + base;
        f32x4 v0 = *(const f32x4*)sp;
        f32x4 v1 = *(const f32x4*)(sp + 4);
#pragma unroll
        for (int t = 0; t < 4; ++t) {
            p[t]     = f2bf(silu_f(v0[t]));
            p[t + 4] = f2bf(silu_f(v1[t]));
        }
    } else {
        const int i = (base - srcCols) >> 3;
        const float xv = src[(size_t)n * srcCols + i];
        const float t = (xv + 2.2f) * 2.5f;               // knot units
        const bool inr = (t >= 0.f) && (t < 11.f);
        const float jf = floorf(t);
        const int j = (int)jf;
        const float f = t - jf;
        const float f2 = f * f, f3 = f2 * f;
        const float s6 = 1.f / 6.f;
        const float w3 = f3 * s6;
        const float w2 = (1.f + 3.f*f + 3.f*f2 - 3.f*f3) * s6;
        const float w1 = (4.f - 6.f*f2 + 3.f*f3) * s6;
        float w0 = 1.f - f; w0 = w0 * w0 * w0 * s6;
#pragma unroll
        for (int c = 0; c < 8; ++c) {
            float v = 0.f;
            v = (j == c)     ? w3 : v;
            v = (j == c + 1) ? w2 : v;
            v = (j == c + 2) ? w1 : v;
            v = (j == c + 3) ? w0 : v;
            v = inr ? v : 0.f;
            p[c] = f2bf(v);
        }
    }
    *(u16x8*)(dst + (size_t)n * 9216 + (size_t)g * 8) = p;
}

// ---------------------------------------------------------------------------
// C[M,N] = A[M,K]*B[N,K]^T (bf16 in, fp32 out). 256x256 tile, BK=64.
// WMODE: 0 = store, 1 = atomicAdd, 2 = load-add-store (split-K partials).
// Split-K via blockIdx.z: k0 = bz*nk*64, C-slice offset bz*zstride.
template <int WMODE>
__global__ __launch_bounds__(512, 2) void gemm256(
    const u16* __restrict__ A, int lda,
    const u16* __restrict__ B, int ldb,
    float* __restrict__ C, int ldc,
    int nk, size_t zstride)
{
    // [buf][mat A/B][K-half][row][32 cols]  (2*2*2*16KB = 128 KiB)
    __shared__ __attribute__((aligned(16))) u16 sm[2][2][2][256][32];

    const int tid  = threadIdx.x;
    const int lane = tid & 63;
    const int wave = tid >> 6;
    const int wr = wave >> 2;          // 0..1
    const int wc = wave & 3;           // 0..3

    // XCD-aware bijective swizzle (all grids here have nwg % 8 == 0)
    const int gx = gridDim.x, gy = gridDim.y, gz = gridDim.z;
    int flat = (blockIdx.z * gy + blockIdx.y) * gx + blockIdx.x;
    const int nwg = gx * gy * gz;
    const int cpx = nwg >> 3;
    flat = (flat & 7) * cpx + (flat >> 3);
    const int bx = flat % gx;
    const int by = (flat / gx) % gy;
    const int bz = flat / (gx * gy);

    const int m0 = by * 256;
    const int n0 = bx * 256;
    const int k0 = bz * nk * 64;

    // --- staging addresses -------------------------------------------------
    // load i of a part covers rows i*128 + (tid>>2); 16B unit u = tid&3 holds
    // logical unit u^((row>>1)&3)  ((row>>1)&3 == (tid>>3)&3 for both i).
    const int sRow  = tid >> 2;
    const int swcol = ((tid & 3) ^ ((tid >> 3) & 3)) * 8;
    const u16* Ag0 = A + (size_t)(m0 + sRow)       * lda + k0 + swcol;
    const u16* Ag1 = A + (size_t)(m0 + 128 + sRow) * lda + k0 + swcol;
    const u16* Bg0 = B + (size_t)(n0 + sRow)       * ldb + k0 + swcol;
    const u16* Bg1 = B + (size_t)(n0 + 128 + sRow) * ldb + k0 + swcol;

    // --- fragment read addressing -------------------------------------------
    // logical 16B unit u' = lane>>4 at row rb+fRow; physical u = u'^((row>>1)&3)
    // = u'^((lane>>1)&3) since rb % 16 == 0.
    const int fRow = lane & 15;
    const int ucol = (((lane >> 4) ^ ((lane >> 1) & 3))) * 8;

    const f32x4 zero = {0.f, 0.f, 0.f, 0.f};
    f32x4 acc[8][4];
#pragma unroll
    for (int a = 0; a < 8; ++a)
#pragma unroll
        for (int b = 0; b < 4; ++b) acc[a][b] = zero;

    // prologue: stage all 4 parts of tile 0 into buf 0 (8 loads/thread)
#pragma unroll
    for (int p = 0; p < 4; ++p) {
        const size_t koff = (size_t)(p >> 1) * 32;
        u16* lb = &sm[0][p & 1][p >> 1][0][0] + wave * 512;
        if ((p & 1) == 0) { llds16(Ag0 + koff, lb); llds16(Ag1 + koff, lb + 4096); }
        else              { llds16(Bg0 + koff, lb); llds16(Bg1 + koff, lb + 4096); }
    }
    asm volatile("s_waitcnt vmcnt(4)" ::: "memory");   // kh0 of tile 0 landed
    __builtin_amdgcn_s_barrier();
    __builtin_amdgcn_sched_barrier(0);

    bf16x8 bb[4];
    for (int kt = 0; kt < nk; ++kt) {
        const int b = kt & 1;
        const int ktn = (kt + 1 < nk) ? kt + 1 : 0;    // wrap keeps counts uniform
#pragma unroll
        for (int p = 0; p < 4; ++p) {
            const int ks = p >> 1, mh = p & 1;
            // ds_read this phase's A frags (and B frags at each ks start)
            bf16x8 af[4];
#pragma unroll
            for (int j = 0; j < 4; ++j)
                af[j] = *(const bf16x8*)
                    &sm[b][0][ks][wr * 128 + mh * 64 + j * 16 + fRow][ucol];
            if (mh == 0) {
#pragma unroll
                for (int nf = 0; nf < 4; ++nf)
                    bb[nf] = *(const bf16x8*)
                        &sm[b][1][ks][wc * 64 + nf * 16 + fRow][ucol];
            }
            // stage part p of tile kt+1 into buf b^1
            {
                const size_t koff = (size_t)ktn * 64 + (size_t)(p >> 1) * 32;
                u16* lb = &sm[b ^ 1][p & 1][p >> 1][0][0] + wave * 512;
                if ((p & 1) == 0) { llds16(Ag0 + koff, lb); llds16(Ag1 + koff, lb + 4096); }
                else              { llds16(Bg0 + koff, lb); llds16(Bg1 + koff, lb + 4096); }
            }
            asm volatile("s_waitcnt lgkmcnt(0)" ::: "memory");
            __builtin_amdgcn_sched_barrier(0);
            __builtin_amdgcn_s_setprio(1);
#pragma unroll
            for (int j = 0; j < 4; ++j)
#pragma unroll
                for (int nf = 0; nf < 4; ++nf)
                    acc[mh * 4 + j][nf] = __builtin_amdgcn_mfma_f32_16x16x32_bf16(
                        af[j], bb[nf], acc[mh * 4 + j][nf], 0, 0, 0);
            __builtin_amdgcn_s_setprio(0);
            __builtin_amdgcn_sched_barrier(0);
            if (p == 1 || p == 3)   // counted wait: oldest K-half landed
                asm volatile("s_waitcnt vmcnt(4)" ::: "memory");
            __builtin_amdgcn_s_barrier();
            __builtin_amdgcn_sched_barrier(0);
        }
    }
    asm volatile("s_waitcnt vmcnt(0)" ::: "memory");   // drain wrap-stage loads

    // epilogue: C/D layout col=lane&15, row=(lane>>4)*4+j
    float* Cz = C + (size_t)bz * zstride;
    const int cRow = m0 + wr * 128 + (lane >> 4) * 4;
    const int cCol = n0 + wc * 64 + (lane & 15);
#pragma unroll
    for (int af = 0; af < 8; ++af)
#pragma unroll
        for (int nf = 0; nf < 4; ++nf)
#pragma unroll
            for (int j = 0; j < 4; ++j) {
                const size_t off = (size_t)(cRow + af * 16 + j) * ldc
                                 + (cCol + nf * 16);
                if (WMODE == 1)      atomicAdd(&Cz[off], acc[af][nf][j]);
                else if (WMODE == 2) Cz[off] += acc[af][nf][j];
                else                 Cz[off] = acc[af][nf][j];
            }
}

// ---------------------------------------------------------------------------
__global__ __launch_bounds__(256) void reduce4(
    const float* __restrict__ z, float* __restrict__ out, int n4, int zstride4)
{
    const int i = blockIdx.x * 256 + threadIdx.x;      // f32x4 index
    if (i >= n4) return;
    const f32x4* p = (const f32x4*)z;
    f32x4 v = p[i];
    v += p[i + zstride4];
    v += p[i + 2 * zstride4];
    v += p[i + 3 * zstride4];
    *(f32x4*)(out + (size_t)i * 4) = v;
}

// ---------------------------------------------------------------------------
extern "C" void kernel_launch(void* const* d_in, const int* in_sizes, int n_in,
                              void* d_out, int out_size, void* d_ws, size_t ws_size,
                              hipStream_t stream) {
    const float* x   = (const float*)d_in[0];
    const float* bw1 = (const float*)d_in[1];
    const float* sw1 = (const float*)d_in[2];
    const float* sc1 = (const float*)d_in[3];
    const float* bw2 = (const float*)d_in[4];
    const float* sw2 = (const float*)d_in[5];
    const float* sc2 = (const float*)d_in[6];
    float* out = (float*)d_out;

    char* ws = (char*)d_ws;
    u16*   regionA = (u16*)ws;                            // 75,497,472 B
    u16*   regionB = (u16*)(ws + 75497472);               // 75,497,472 B
    float* hbuf    = (float*)(ws + 150994944);            // 67,108,864 B
    float* zbuf    = (float*)(ws + 218103808);            // 67,108,864 B (opt)
    const bool useZ = ws_size >= 285212672ull;
    const size_t ZS = (size_t)NTOK * D_MODEL;             // 4,194,304 elems

    if (!useZ)  // layer-2 GEMM accumulates atomically into out
        hipMemsetAsync(d_out, 0, ZS * sizeof(float), stream);

    // ---- layer 1 ----
    build_w<<<16384, 256, 0, stream>>>(bw1, sw1, sc1, regionA, D_MODEL, 10);
    build_act<<<dim3(9, NTOK), 128, 0, stream>>>(x, D_MODEL, regionB, 0);
    gemm256<0><<<dim3(16, 16, 1), 512, 0, stream>>>(
        regionB, K1, regionA, K1, hbuf, D_FF, 144, 0);

    // ---- layer 2: 4 K-chunks, each split-K z=4 (256 blocks/dispatch) ----
    build_w<<<16384, 256, 0, stream>>>(bw2, sw2, sc2, regionB, D_FF, 12);
    for (int ck = 0; ck < 4; ++ck) {
        build_act<<<dim3(9, NTOK), 128, 0, stream>>>(hbuf, D_FF, regionA, ck * KCHUNK);
        if (useZ) {
            if (ck == 0)
                gemm256<0><<<dim3(4, 16, 4), 512, 0, stream>>>(
                    regionA, KCHUNK, regionB + (size_t)ck * KCHUNK, K2,
                    zbuf, D_MODEL, 36, ZS);
            else
                gemm256<2><<<dim3(4, 16, 4), 512, 0, stream>>>(
                    regionA, KCHUNK, regionB + (size_t)ck * KCHUNK, K2,
                    zbuf, D_MODEL, 36, ZS);
        } else {
            gemm256<1><<<dim3(4, 16, 4), 512, 0, stream>>>(
                regionA, KCHUNK, regionB + (size_t)ck * KCHUNK, K2,
                out, D_MODEL, 36, ZS);
        }
    }
    if (useZ)
        reduce4<<<(int)(ZS / 4 / 256), 256, 0, stream>>>(zbuf, out, (int)(ZS / 4), (int)(ZS / 4));
}

// Round 8
// 959.560 us; speedup vs baseline: 1.7743x; 1.0943x over previous
//
#include <hip/hip_runtime.h>

// KAN FFN on MI355X. Each KAN linear = one bf16 GEMM over concatenated
// [silu(x) | cubic b-spline bases] activation (K = 9*d_in) vs
// [base_w | spline_w*scaler], fp32 accumulate.
//
// GEMM: 256x256 tile, BK=64 split in two K-halves, 8 waves (2Mx4N),
// 4 phases/K-tile, counted vmcnt(4) (never 0 in main loop), XOR swizzle on
// 16B units (inverse-swizzled global source + swizzled ds_read), setprio
// around MFMA, XCD block swizzle.
//
// Tier A (ws >= 444.6 MB): layer 2 as ONE full-K GEMM over a fully
//   materialized Act2, split-K z=4 into non-RMW partials + reduce.
//   Layout: [0,302M) Act2 (Act1 at [0,75.5M) + W1aug at [75.5M,151M) live
//   here during layer 1, dead before Act2 is written); [302M,369M) h -> zbuf;
//   [369M,444.6M) W2aug.
// Tier B (ws >= 285.2 MB): round-3 chunked path (4 x K=9216 chunks, z=4
//   partials accumulated via load-add-store) + reduce.
// Tier C: chunked with atomicAdd into d_out.

typedef unsigned short u16;
typedef __bf16 bf16x8 __attribute__((ext_vector_type(8)));
typedef float f32x4 __attribute__((ext_vector_type(4)));
typedef u16 u16x8 __attribute__((ext_vector_type(8)));

#define D_MODEL 1024
#define D_FF    4096
#define NTOK    4096
#define K1      9216    // 9*1024
#define K2      36864   // 9*4096
#define KCHUNK  9216    // K2 / 4

__device__ __forceinline__ u16 f2bf(float v) {
    union { float f; unsigned u; } a; a.f = v;
    unsigned r = a.u + 0x7FFFu + ((a.u >> 16) & 1u);  // RNE
    return (u16)(r >> 16);
}

__device__ __forceinline__ float silu_f(float x) {
    return x / (1.f + __expf(-x));
}

__device__ __forceinline__ void llds16(const u16* g, u16* l) {
    __builtin_amdgcn_global_load_lds(
        (__attribute__((address_space(1))) void*)(u16*)g,
        (__attribute__((address_space(3))) void*)l,
        16, 0, 0);
}

// ---------------------------------------------------------------------------
__global__ __launch_bounds__(256) void build_w(
    const float* __restrict__ bw, const float* __restrict__ sw,
    const float* __restrict__ sc, u16* __restrict__ dst,
    int IN, int shift)
{
    const int idx = blockIdx.x * 256 + threadIdx.x;      // o*IN + i
    const int o = idx >> shift;
    const int i = idx & (IN - 1);
    const int rowLen = IN * 9;
    const float scv = sc[idx];
    const float* sp = sw + (size_t)idx * 8;
    f32x4 s0 = *(const f32x4*)sp;
    f32x4 s1 = *(const f32x4*)(sp + 4);
    u16x8 p;
#pragma unroll
    for (int t = 0; t < 4; ++t) {
        p[t]     = f2bf(s0[t] * scv);
        p[t + 4] = f2bf(s1[t] * scv);
    }
    dst[(size_t)o * rowLen + i] = f2bf(bw[idx]);
    *(u16x8*)(dst + (size_t)o * rowLen + IN + (size_t)i * 8) = p;
}

// ---------------------------------------------------------------------------
__global__ __launch_bounds__(128) void build_act(
    const float* __restrict__ src, int srcCols,
    u16* __restrict__ dst, int col0, int ldDst)
{
    const int g = blockIdx.x * 128 + threadIdx.x;        // group of 8 cols
    const int n = blockIdx.y;
    const int base = col0 + g * 8;
    u16x8 p;
    if (base < srcCols) {
        const float* sp = src + (size_t)n * srcCols + base;
        f32x4 v0 = *(const f32x4*)sp;
        f32x4 v1 = *(const f32x4*)(sp + 4);
#pragma unroll
        for (int t = 0; t < 4; ++t) {
            p[t]     = f2bf(silu_f(v0[t]));
            p[t + 4] = f2bf(silu_f(v1[t]));
        }
    } else {
        const int i = (base - srcCols) >> 3;
        const float xv = src[(size_t)n * srcCols + i];
        const float t = (xv + 2.2f) * 2.5f;               // knot units
        const bool inr = (t >= 0.f) && (t < 11.f);
        const float jf = floorf(t);
        const int j = (int)jf;
        const float f = t - jf;
        const float f2 = f * f, f3 = f2 * f;
        const float s6 = 1.f / 6.f;
        const float w3 = f3 * s6;
        const float w2 = (1.f + 3.f*f + 3.f*f2 - 3.f*f3) * s6;
        const float w1 = (4.f - 6.f*f2 + 3.f*f3) * s6;
        float w0 = 1.f - f; w0 = w0 * w0 * w0 * s6;
#pragma unroll
        for (int c = 0; c < 8; ++c) {
            float v = 0.f;
            v = (j == c)     ? w3 : v;
            v = (j == c + 1) ? w2 : v;
            v = (j == c + 2) ? w1 : v;
            v = (j == c + 3) ? w0 : v;
            v = inr ? v : 0.f;
            p[c] = f2bf(v);
        }
    }
    *(u16x8*)(dst + (size_t)n * ldDst + (size_t)g * 8) = p;
}

// ---------------------------------------------------------------------------
// C[M,N] = A[M,K]*B[N,K]^T (bf16 in, fp32 out). 256x256 tile, BK=64.
// WMODE: 0 = store, 1 = atomicAdd, 2 = load-add-store (split-K partials).
// Split-K via blockIdx.z: k0 = bz*nk*64, C-slice offset bz*zstride.
template <int WMODE>
__global__ __launch_bounds__(512, 2) void gemm256(
    const u16* __restrict__ A, int lda,
    const u16* __restrict__ B, int ldb,
    float* __restrict__ C, int ldc,
    int nk, size_t zstride)
{
    // [buf][mat A/B][K-half][row][32 cols]  (2*2*2*16KB = 128 KiB)
    __shared__ __attribute__((aligned(16))) u16 sm[2][2][2][256][32];

    const int tid  = threadIdx.x;
    const int lane = tid & 63;
    const int wave = tid >> 6;
    const int wr = wave >> 2;          // 0..1
    const int wc = wave & 3;           // 0..3

    // XCD-aware bijective swizzle (all grids here have nwg % 8 == 0)
    const int gx = gridDim.x, gy = gridDim.y, gz = gridDim.z;
    int flat = (blockIdx.z * gy + blockIdx.y) * gx + blockIdx.x;
    const int nwg = gx * gy * gz;
    const int cpx = nwg >> 3;
    flat = (flat & 7) * cpx + (flat >> 3);
    const int bx = flat % gx;
    const int by = (flat / gx) % gy;
    const int bz = flat / (gx * gy);

    const int m0 = by * 256;
    const int n0 = bx * 256;
    const int k0 = bz * nk * 64;

    // staging: load i of part p covers rows i*128 + (tid>>2); 16B unit
    // u = tid&3 holds logical unit u^((row>>1)&3) (== u^((tid>>3)&3)).
    const int sRow  = tid >> 2;
    const int swcol = ((tid & 3) ^ ((tid >> 3) & 3)) * 8;
    const u16* Ag0 = A + (size_t)(m0 + sRow)       * lda + k0 + swcol;
    const u16* Ag1 = A + (size_t)(m0 + 128 + sRow) * lda + k0 + swcol;
    const u16* Bg0 = B + (size_t)(n0 + sRow)       * ldb + k0 + swcol;
    const u16* Bg1 = B + (size_t)(n0 + 128 + sRow) * ldb + k0 + swcol;

    // fragment reads: logical unit u' = lane>>4 at row rb+fRow;
    // physical u = u' ^ ((lane>>1)&3) since rb % 16 == 0.
    const int fRow = lane & 15;
    const int ucol = (((lane >> 4) ^ ((lane >> 1) & 3))) * 8;

    const f32x4 zero = {0.f, 0.f, 0.f, 0.f};
    f32x4 acc[8][4];
#pragma unroll
    for (int a = 0; a < 8; ++a)
#pragma unroll
        for (int b = 0; b < 4; ++b) acc[a][b] = zero;

    // prologue: stage all 4 parts of tile 0 into buf 0 (8 loads/thread)
#pragma unroll
    for (int p = 0; p < 4; ++p) {
        const size_t koff = (size_t)(p >> 1) * 32;
        u16* lb = &sm[0][p & 1][p >> 1][0][0] + wave * 512;
        if ((p & 1) == 0) { llds16(Ag0 + koff, lb); llds16(Ag1 + koff, lb + 4096); }
        else              { llds16(Bg0 + koff, lb); llds16(Bg1 + koff, lb + 4096); }
    }
    asm volatile("s_waitcnt vmcnt(4)" ::: "memory");   // kh0 of tile 0 landed
    __builtin_amdgcn_s_barrier();
    __builtin_amdgcn_sched_barrier(0);

    bf16x8 bb[4];
    for (int kt = 0; kt < nk; ++kt) {
        const int b = kt & 1;
        const int ktn = (kt + 1 < nk) ? kt + 1 : 0;    // wrap keeps counts uniform
#pragma unroll
        for (int p = 0; p < 4; ++p) {
            const int ks = p >> 1, mh = p & 1;
            bf16x8 af[4];
#pragma unroll
            for (int j = 0; j < 4; ++j)
                af[j] = *(const bf16x8*)
                    &sm[b][0][ks][wr * 128 + mh * 64 + j * 16 + fRow][ucol];
            if (mh == 0) {
#pragma unroll
                for (int nf = 0; nf < 4; ++nf)
                    bb[nf] = *(const bf16x8*)
                        &sm[b][1][ks][wc * 64 + nf * 16 + fRow][ucol];
            }
            // stage part p of tile kt+1 into buf b^1
            {
                const size_t koff = (size_t)ktn * 64 + (size_t)(p >> 1) * 32;
                u16* lb = &sm[b ^ 1][p & 1][p >> 1][0][0] + wave * 512;
                if ((p & 1) == 0) { llds16(Ag0 + koff, lb); llds16(Ag1 + koff, lb + 4096); }
                else              { llds16(Bg0 + koff, lb); llds16(Bg1 + koff, lb + 4096); }
            }
            asm volatile("s_waitcnt lgkmcnt(0)" ::: "memory");
            __builtin_amdgcn_sched_barrier(0);
            __builtin_amdgcn_s_setprio(1);
#pragma unroll
            for (int j = 0; j < 4; ++j)
#pragma unroll
                for (int nf = 0; nf < 4; ++nf)
                    acc[mh * 4 + j][nf] = __builtin_amdgcn_mfma_f32_16x16x32_bf16(
                        af[j], bb[nf], acc[mh * 4 + j][nf], 0, 0, 0);
            __builtin_amdgcn_s_setprio(0);
            __builtin_amdgcn_sched_barrier(0);
            if (p == 1 || p == 3)   // counted wait: oldest K-half landed
                asm volatile("s_waitcnt vmcnt(4)" ::: "memory");
            __builtin_amdgcn_s_barrier();
            __builtin_amdgcn_sched_barrier(0);
        }
    }
    asm volatile("s_waitcnt vmcnt(0)" ::: "memory");   // drain wrap-stage loads

    // epilogue: C/D layout col=lane&15, row=(lane>>4)*4+j
    float* Cz = C + (size_t)bz * zstride;
    const int cRow = m0 + wr * 128 + (lane >> 4) * 4;
    const int cCol = n0 + wc * 64 + (lane & 15);
#pragma unroll
    for (int af = 0; af < 8; ++af)
#pragma unroll
        for (int nf = 0; nf < 4; ++nf)
#pragma unroll
            for (int j = 0; j < 4; ++j) {
                const size_t off = (size_t)(cRow + af * 16 + j) * ldc
                                 + (cCol + nf * 16);
                if (WMODE == 1)      atomicAdd(&Cz[off], acc[af][nf][j]);
                else if (WMODE == 2) Cz[off] += acc[af][nf][j];
                else                 Cz[off] = acc[af][nf][j];
            }
}

// ---------------------------------------------------------------------------
__global__ __launch_bounds__(256) void reduce4(
    const float* __restrict__ z, float* __restrict__ out, int n4, int zstride4)
{
    const int i = blockIdx.x * 256 + threadIdx.x;      // f32x4 index
    if (i >= n4) return;
    const f32x4* p = (const f32x4*)z;
    f32x4 v = p[i];
    v += p[i + zstride4];
    v += p[i + 2 * zstride4];
    v += p[i + 3 * zstride4];
    *(f32x4*)(out + (size_t)i * 4) = v;
}

// ---------------------------------------------------------------------------
extern "C" void kernel_launch(void* const* d_in, const int* in_sizes, int n_in,
                              void* d_out, int out_size, void* d_ws, size_t ws_size,
                              hipStream_t stream) {
    const float* x   = (const float*)d_in[0];
    const float* bw1 = (const float*)d_in[1];
    const float* sw1 = (const float*)d_in[2];
    const float* sc1 = (const float*)d_in[3];
    const float* bw2 = (const float*)d_in[4];
    const float* sw2 = (const float*)d_in[5];
    const float* sc2 = (const float*)d_in[6];
    float* out = (float*)d_out;

    char* ws = (char*)d_ws;
    const size_t ZS = (size_t)NTOK * D_MODEL;             // 4,194,304 elems

    // ---- Tier A: full Act2, single layer-2 GEMM (needs 444,596,224 B) ----
    if (ws_size >= 444596224ull) {
        u16*   act2  = (u16*)ws;                          // [0, 301,989,888)
        u16*   act1  = (u16*)ws;                          // [0, 75,497,472)   (inside act2, dead later)
        u16*   w1    = (u16*)(ws + 75497472);             // [75.5M, 151M)     (inside act2, dead later)
        float* hbuf  = (float*)(ws + 301989888);          // [302M, 369M)  -> zbuf
        float* zbuf  = (float*)(ws + 301989888);
        u16*   w2    = (u16*)(ws + 369098752);            // [369M, 444.6M)

        build_w<<<16384, 256, 0, stream>>>(bw1, sw1, sc1, w1, D_MODEL, 10);
        build_act<<<dim3(9, NTOK), 128, 0, stream>>>(x, D_MODEL, act1, 0, K1);
        gemm256<0><<<dim3(16, 16, 1), 512, 0, stream>>>(
            act1, K1, w1, K1, hbuf, D_FF, 144, 0);

        build_w<<<16384, 256, 0, stream>>>(bw2, sw2, sc2, w2, D_FF, 12);
        build_act<<<dim3(36, NTOK), 128, 0, stream>>>(hbuf, D_FF, act2, 0, K2);
        // h is dead now; zbuf aliases it (written strictly after last read).
        gemm256<0><<<dim3(4, 16, 4), 512, 0, stream>>>(
            act2, K2, w2, K2, zbuf, D_MODEL, 144, ZS);
        reduce4<<<(int)(ZS / 4 / 256), 256, 0, stream>>>(
            zbuf, out, (int)(ZS / 4), (int)(ZS / 4));
        return;
    }

    // ---- Tier B/C: round-3 chunked fallback ----
    u16*   regionA = (u16*)ws;                            // 75,497,472 B
    u16*   regionB = (u16*)(ws + 75497472);               // 75,497,472 B
    float* hbuf    = (float*)(ws + 150994944);            // 67,108,864 B
    float* zbuf    = (float*)(ws + 218103808);            // 67,108,864 B (opt)
    const bool useZ = ws_size >= 285212672ull;

    if (!useZ)
        hipMemsetAsync(d_out, 0, ZS * sizeof(float), stream);

    build_w<<<16384, 256, 0, stream>>>(bw1, sw1, sc1, regionA, D_MODEL, 10);
    build_act<<<dim3(9, NTOK), 128, 0, stream>>>(x, D_MODEL, regionB, 0, K1);
    gemm256<0><<<dim3(16, 16, 1), 512, 0, stream>>>(
        regionB, K1, regionA, K1, hbuf, D_FF, 144, 0);

    build_w<<<16384, 256, 0, stream>>>(bw2, sw2, sc2, regionB, D_FF, 12);
    for (int ck = 0; ck < 4; ++ck) {
        build_act<<<dim3(9, NTOK), 128, 0, stream>>>(hbuf, D_FF, regionA, ck * KCHUNK, K1);
        if (useZ) {
            if (ck == 0)
                gemm256<0><<<dim3(4, 16, 4), 512, 0, stream>>>(
                    regionA, KCHUNK, regionB + (size_t)ck * KCHUNK, K2,
                    zbuf, D_MODEL, 36, ZS);
            else
                gemm256<2><<<dim3(4, 16, 4), 512, 0, stream>>>(
                    regionA, KCHUNK, regionB + (size_t)ck * KCHUNK, K2,
                    zbuf, D_MODEL, 36, ZS);
        } else {
            gemm256<1><<<dim3(4, 16, 4), 512, 0, stream>>>(
                regionA, KCHUNK, regionB + (size_t)ck * KCHUNK, K2,
                out, D_MODEL, 36, ZS);
        }
    }
    if (useZ)
        reduce4<<<(int)(ZS / 4 / 256), 256, 0, stream>>>(
            zbuf, out, (int)(ZS / 4), (int)(ZS / 4));
}

// Round 9
// 952.682 us; speedup vs baseline: 1.7872x; 1.0072x over previous
//
#include <hip/hip_runtime.h>

// KAN FFN on MI355X. Each KAN linear = one bf16 GEMM over concatenated
// [silu(x) | cubic b-spline bases] activation (K = 9*d_in) vs
// [base_w | spline_w*scaler], fp32 accumulate.
//
// GEMM: 256x256 tile, BK=64 split in two K-halves, 8 waves (2Mx4N),
// 4 phases/K-tile, counted vmcnt(4) (never 0 in main loop), XOR swizzle on
// 16B units (inverse-swizzled global source + swizzled ds_read), setprio
// around MFMA, XCD block swizzle.
//
// Tier F (ws >= 452,984,832): gemm1's epilogue DIRECTLY emits act2
//   (silu bf16 + 8 spline bases per h element) -- h never materialized,
//   build_act2 eliminated. Layout: [0,302M) act2; [302M,377.5M) act1 -> w2;
//   [377.5M,453M) w1 -> zbuf(67M). Layer 2 = one full-K GEMM, split-K z=4
//   non-RMW partials + reduce.
// Tier A (ws >= 444.6 MB): round-8 path (separate build_act2 pass).
// Tier B (ws >= 285.2 MB): chunked K with z=4 partials + reduce.
// Tier C: chunked with atomicAdd into d_out.

typedef unsigned short u16;
typedef __bf16 bf16x8 __attribute__((ext_vector_type(8)));
typedef float f32x4 __attribute__((ext_vector_type(4)));
typedef u16 u16x8 __attribute__((ext_vector_type(8)));

#define D_MODEL 1024
#define D_FF    4096
#define NTOK    4096
#define K1      9216    // 9*1024
#define K2      36864   // 9*4096
#define KCHUNK  9216    // K2 / 4

__device__ __forceinline__ u16 f2bf(float v) {
    union { float f; unsigned u; } a; a.f = v;
    unsigned r = a.u + 0x7FFFu + ((a.u >> 16) & 1u);  // RNE
    return (u16)(r >> 16);
}

__device__ __forceinline__ float silu_f(float x) {
    return x / (1.f + __expf(-x));
}

// cubic b-spline bases (grid 5, order 3): 8 coefficients for one x
__device__ __forceinline__ u16x8 bases8(float xv) {
    const float t = (xv + 2.2f) * 2.5f;               // knot units
    const bool inr = (t >= 0.f) && (t < 11.f);
    const float jf = floorf(t);
    const int j = (int)jf;
    const float f = t - jf;
    const float f2 = f * f, f3 = f2 * f;
    const float s6 = 1.f / 6.f;
    const float w3 = f3 * s6;
    const float w2 = (1.f + 3.f*f + 3.f*f2 - 3.f*f3) * s6;
    const float w1 = (4.f - 6.f*f2 + 3.f*f3) * s6;
    float w0 = 1.f - f; w0 = w0 * w0 * w0 * s6;
    u16x8 p;
#pragma unroll
    for (int c = 0; c < 8; ++c) {
        float v = 0.f;
        v = (j == c)     ? w3 : v;
        v = (j == c + 1) ? w2 : v;
        v = (j == c + 2) ? w1 : v;
        v = (j == c + 3) ? w0 : v;
        v = inr ? v : 0.f;
        p[c] = f2bf(v);
    }
    return p;
}

__device__ __forceinline__ void llds16(const u16* g, u16* l) {
    __builtin_amdgcn_global_load_lds(
        (__attribute__((address_space(1))) void*)(u16*)g,
        (__attribute__((address_space(3))) void*)l,
        16, 0, 0);
}

// ---------------------------------------------------------------------------
__global__ __launch_bounds__(256) void build_w(
    const float* __restrict__ bw, const float* __restrict__ sw,
    const float* __restrict__ sc, u16* __restrict__ dst,
    int IN, int shift)
{
    const int idx = blockIdx.x * 256 + threadIdx.x;      // o*IN + i
    const int o = idx >> shift;
    const int i = idx & (IN - 1);
    const int rowLen = IN * 9;
    const float scv = sc[idx];
    const float* sp = sw + (size_t)idx * 8;
    f32x4 s0 = *(const f32x4*)sp;
    f32x4 s1 = *(const f32x4*)(sp + 4);
    u16x8 p;
#pragma unroll
    for (int t = 0; t < 4; ++t) {
        p[t]     = f2bf(s0[t] * scv);
        p[t + 4] = f2bf(s1[t] * scv);
    }
    dst[(size_t)o * rowLen + i] = f2bf(bw[idx]);
    *(u16x8*)(dst + (size_t)o * rowLen + IN + (size_t)i * 8) = p;
}

// ---------------------------------------------------------------------------
__global__ __launch_bounds__(128) void build_act(
    const float* __restrict__ src, int srcCols,
    u16* __restrict__ dst, int col0, int ldDst)
{
    const int g = blockIdx.x * 128 + threadIdx.x;        // group of 8 cols
    const int n = blockIdx.y;
    const int base = col0 + g * 8;
    u16x8 p;
    if (base < srcCols) {
        const float* sp = src + (size_t)n * srcCols + base;
        f32x4 v0 = *(const f32x4*)sp;
        f32x4 v1 = *(const f32x4*)(sp + 4);
#pragma unroll
        for (int t = 0; t < 4; ++t) {
            p[t]     = f2bf(silu_f(v0[t]));
            p[t + 4] = f2bf(silu_f(v1[t]));
        }
    } else {
        const int i = (base - srcCols) >> 3;
        p = bases8(src[(size_t)n * srcCols + i]);
    }
    *(u16x8*)(dst + (size_t)n * ldDst + (size_t)g * 8) = p;
}

// ---------------------------------------------------------------------------
// C[M,N] = A[M,K]*B[N,K]^T (bf16 in, fp32 out). 256x256 tile, BK=64.
// WMODE: 0 = store, 1 = atomicAdd, 2 = load-add-store, 3 = KAN-fused
// epilogue (emit silu+bases bf16 into actOut rows of length K2; no C write).
// Split-K via blockIdx.z: k0 = bz*nk*64, C-slice offset bz*zstride.
template <int WMODE>
__global__ __launch_bounds__(512, 2) void gemm256(
    const u16* __restrict__ A, int lda,
    const u16* __restrict__ B, int ldb,
    float* __restrict__ C, int ldc,
    int nk, size_t zstride, u16* __restrict__ actOut)
{
    // [buf][mat A/B][K-half][row][32 cols]  (2*2*2*16KB = 128 KiB)
    __shared__ __attribute__((aligned(16))) u16 sm[2][2][2][256][32];

    const int tid  = threadIdx.x;
    const int lane = tid & 63;
    const int wave = tid >> 6;
    const int wr = wave >> 2;          // 0..1
    const int wc = wave & 3;           // 0..3

    // XCD-aware bijective swizzle (all grids here have nwg % 8 == 0)
    const int gx = gridDim.x, gy = gridDim.y, gz = gridDim.z;
    int flat = (blockIdx.z * gy + blockIdx.y) * gx + blockIdx.x;
    const int nwg = gx * gy * gz;
    const int cpx = nwg >> 3;
    flat = (flat & 7) * cpx + (flat >> 3);
    const int bx = flat % gx;
    const int by = (flat / gx) % gy;
    const int bz = flat / (gx * gy);

    const int m0 = by * 256;
    const int n0 = bx * 256;
    const int k0 = bz * nk * 64;

    // staging: load i of part p covers rows i*128 + (tid>>2); 16B unit
    // u = tid&3 holds logical unit u^((row>>1)&3) (== u^((tid>>3)&3)).
    const int sRow  = tid >> 2;
    const int swcol = ((tid & 3) ^ ((tid >> 3) & 3)) * 8;
    const u16* Ag0 = A + (size_t)(m0 + sRow)       * lda + k0 + swcol;
    const u16* Ag1 = A + (size_t)(m0 + 128 + sRow) * lda + k0 + swcol;
    const u16* Bg0 = B + (size_t)(n0 + sRow)       * ldb + k0 + swcol;
    const u16* Bg1 = B + (size_t)(n0 + 128 + sRow) * ldb + k0 + swcol;

    // fragment reads: logical unit u' = lane>>4 at row rb+fRow;
    // physical u = u' ^ ((lane>>1)&3) since rb % 16 == 0.
    const int fRow = lane & 15;
    const int ucol = (((lane >> 4) ^ ((lane >> 1) & 3))) * 8;

    const f32x4 zero = {0.f, 0.f, 0.f, 0.f};
    f32x4 acc[8][4];
#pragma unroll
    for (int a = 0; a < 8; ++a)
#pragma unroll
        for (int b = 0; b < 4; ++b) acc[a][b] = zero;

    // prologue: stage all 4 parts of tile 0 into buf 0 (8 loads/thread)
#pragma unroll
    for (int p = 0; p < 4; ++p) {
        const size_t koff = (size_t)(p >> 1) * 32;
        u16* lb = &sm[0][p & 1][p >> 1][0][0] + wave * 512;
        if ((p & 1) == 0) { llds16(Ag0 + koff, lb); llds16(Ag1 + koff, lb + 4096); }
        else              { llds16(Bg0 + koff, lb); llds16(Bg1 + koff, lb + 4096); }
    }
    asm volatile("s_waitcnt vmcnt(4)" ::: "memory");   // kh0 of tile 0 landed
    __builtin_amdgcn_s_barrier();
    __builtin_amdgcn_sched_barrier(0);

    bf16x8 bb[4];
    for (int kt = 0; kt < nk; ++kt) {
        const int b = kt & 1;
        const int ktn = (kt + 1 < nk) ? kt + 1 : 0;    // wrap keeps counts uniform
#pragma unroll
        for (int p = 0; p < 4; ++p) {
            const int ks = p >> 1, mh = p & 1;
            bf16x8 af[4];
#pragma unroll
            for (int j = 0; j < 4; ++j)
                af[j] = *(const bf16x8*)
                    &sm[b][0][ks][wr * 128 + mh * 64 + j * 16 + fRow][ucol];
            if (mh == 0) {
#pragma unroll
                for (int nf = 0; nf < 4; ++nf)
                    bb[nf] = *(const bf16x8*)
                        &sm[b][1][ks][wc * 64 + nf * 16 + fRow][ucol];
            }
            // stage part p of tile kt+1 into buf b^1
            {
                const size_t koff = (size_t)ktn * 64 + (size_t)(p >> 1) * 32;
                u16* lb = &sm[b ^ 1][p & 1][p >> 1][0][0] + wave * 512;
                if ((p & 1) == 0) { llds16(Ag0 + koff, lb); llds16(Ag1 + koff, lb + 4096); }
                else              { llds16(Bg0 + koff, lb); llds16(Bg1 + koff, lb + 4096); }
            }
            asm volatile("s_waitcnt lgkmcnt(0)" ::: "memory");
            __builtin_amdgcn_sched_barrier(0);
            __builtin_amdgcn_s_setprio(1);
#pragma unroll
            for (int j = 0; j < 4; ++j)
#pragma unroll
                for (int nf = 0; nf < 4; ++nf)
                    acc[mh * 4 + j][nf] = __builtin_amdgcn_mfma_f32_16x16x32_bf16(
                        af[j], bb[nf], acc[mh * 4 + j][nf], 0, 0, 0);
            __builtin_amdgcn_s_setprio(0);
            __builtin_amdgcn_sched_barrier(0);
            if (p == 1 || p == 3)   // counted wait: oldest K-half landed
                asm volatile("s_waitcnt vmcnt(4)" ::: "memory");
            __builtin_amdgcn_s_barrier();
            __builtin_amdgcn_sched_barrier(0);
        }
    }
    asm volatile("s_waitcnt vmcnt(0)" ::: "memory");   // drain wrap-stage loads

    // epilogue: C/D layout col=lane&15, row=(lane>>4)*4+j
    const int cRow = m0 + wr * 128 + (lane >> 4) * 4;
    const int cCol = n0 + wc * 64 + (lane & 15);
    if (WMODE == 3) {
        // emit act2 row fragments: silu(h) at [row][col], bases at
        // [row][D_FF + col*8]. Lanes 0-15 share a row -> the 16B basis
        // stores cover 256B contiguous per 16-lane group.
#pragma unroll
        for (int af = 0; af < 8; ++af)
#pragma unroll
            for (int nf = 0; nf < 4; ++nf)
#pragma unroll
                for (int j = 0; j < 4; ++j) {
                    const int row = cRow + af * 16 + j;
                    const int col = cCol + nf * 16;
                    const float v = acc[af][nf][j];
                    u16* rowp = actOut + (size_t)row * K2;
                    rowp[col] = f2bf(silu_f(v));
                    *(u16x8*)(rowp + D_FF + (size_t)col * 8) = bases8(v);
                }
    } else {
        float* Cz = C + (size_t)bz * zstride;
#pragma unroll
        for (int af = 0; af < 8; ++af)
#pragma unroll
            for (int nf = 0; nf < 4; ++nf)
#pragma unroll
                for (int j = 0; j < 4; ++j) {
                    const size_t off = (size_t)(cRow + af * 16 + j) * ldc
                                     + (cCol + nf * 16);
                    if (WMODE == 1)      atomicAdd(&Cz[off], acc[af][nf][j]);
                    else if (WMODE == 2) Cz[off] += acc[af][nf][j];
                    else                 Cz[off] = acc[af][nf][j];
                }
    }
}

// ---------------------------------------------------------------------------
__global__ __launch_bounds__(256) void reduce4(
    const float* __restrict__ z, float* __restrict__ out, int n4, int zstride4)
{
    const int i = blockIdx.x * 256 + threadIdx.x;      // f32x4 index
    if (i >= n4) return;
    const f32x4* p = (const f32x4*)z;
    f32x4 v = p[i];
    v += p[i + zstride4];
    v += p[i + 2 * zstride4];
    v += p[i + 3 * zstride4];
    *(f32x4*)(out + (size_t)i * 4) = v;
}

// ---------------------------------------------------------------------------
extern "C" void kernel_launch(void* const* d_in, const int* in_sizes, int n_in,
                              void* d_out, int out_size, void* d_ws, size_t ws_size,
                              hipStream_t stream) {
    const float* x   = (const float*)d_in[0];
    const float* bw1 = (const float*)d_in[1];
    const float* sw1 = (const float*)d_in[2];
    const float* sc1 = (const float*)d_in[3];
    const float* bw2 = (const float*)d_in[4];
    const float* sw2 = (const float*)d_in[5];
    const float* sc2 = (const float*)d_in[6];
    float* out = (float*)d_out;

    char* ws = (char*)d_ws;
    const size_t ZS = (size_t)NTOK * D_MODEL;             // 4,194,304 elems

    // ---- Tier F: fused act2 epilogue (needs 452,984,832 B) ----
    if (ws_size >= 452984832ull) {
        u16* act2 = (u16*)ws;                             // [0, 302M)
        u16* rX   = (u16*)(ws + 301989888);               // act1, later w2
        u16* rY   = (u16*)(ws + 377487360);               // w1, later zbuf
        float* zbuf = (float*)(ws + 377487360);

        build_w<<<16384, 256, 0, stream>>>(bw1, sw1, sc1, rY, D_MODEL, 10);
        build_act<<<dim3(9, NTOK), 128, 0, stream>>>(x, D_MODEL, rX, 0, K1);
        gemm256<3><<<dim3(16, 16, 1), 512, 0, stream>>>(
            rX, K1, rY, K1, nullptr, 0, 144, 0, act2);

        build_w<<<16384, 256, 0, stream>>>(bw2, sw2, sc2, rX, D_FF, 12);
        gemm256<0><<<dim3(4, 16, 4), 512, 0, stream>>>(
            act2, K2, rX, K2, zbuf, D_MODEL, 144, ZS, nullptr);
        reduce4<<<(int)(ZS / 4 / 256), 256, 0, stream>>>(
            zbuf, out, (int)(ZS / 4), (int)(ZS / 4));
        return;
    }

    // ---- Tier A: round-8 path (needs 444,596,224 B) ----
    if (ws_size >= 444596224ull) {
        u16*   act2  = (u16*)ws;                          // [0, 302M)
        u16*   act1  = (u16*)ws;                          // [0, 75.5M)  (inside act2, dead later)
        u16*   w1    = (u16*)(ws + 75497472);             // [75.5M,151M) (inside act2, dead later)
        float* hbuf  = (float*)(ws + 301989888);          // [302M,369M) -> zbuf
        float* zbuf  = (float*)(ws + 301989888);
        u16*   w2    = (u16*)(ws + 369098752);            // [369M,444.6M)

        build_w<<<16384, 256, 0, stream>>>(bw1, sw1, sc1, w1, D_MODEL, 10);
        build_act<<<dim3(9, NTOK), 128, 0, stream>>>(x, D_MODEL, act1, 0, K1);
        gemm256<0><<<dim3(16, 16, 1), 512, 0, stream>>>(
            act1, K1, w1, K1, hbuf, D_FF, 144, 0, nullptr);

        build_w<<<16384, 256, 0, stream>>>(bw2, sw2, sc2, w2, D_FF, 12);
        build_act<<<dim3(36, NTOK), 128, 0, stream>>>(hbuf, D_FF, act2, 0, K2);
        gemm256<0><<<dim3(4, 16, 4), 512, 0, stream>>>(
            act2, K2, w2, K2, zbuf, D_MODEL, 144, ZS, nullptr);
        reduce4<<<(int)(ZS / 4 / 256), 256, 0, stream>>>(
            zbuf, out, (int)(ZS / 4), (int)(ZS / 4));
        return;
    }

    // ---- Tier B/C: chunked fallback ----
    u16*   regionA = (u16*)ws;                            // 75,497,472 B
    u16*   regionB = (u16*)(ws + 75497472);               // 75,497,472 B
    float* hbuf    = (float*)(ws + 150994944);            // 67,108,864 B
    float* zbuf    = (float*)(ws + 218103808);            // 67,108,864 B (opt)
    const bool useZ = ws_size >= 285212672ull;

    if (!useZ)
        hipMemsetAsync(d_out, 0, ZS * sizeof(float), stream);

    build_w<<<16384, 256, 0, stream>>>(bw1, sw1, sc1, regionA, D_MODEL, 10);
    build_act<<<dim3(9, NTOK), 128, 0, stream>>>(x, D_MODEL, regionB, 0, K1);
    gemm256<0><<<dim3(16, 16, 1), 512, 0, stream>>>(
        regionB, K1, regionA, K1, hbuf, D_FF, 144, 0, nullptr);

    build_w<<<16384, 256, 0, stream>>>(bw2, sw2, sc2, regionB, D_FF, 12);
    for (int ck = 0; ck < 4; ++ck) {
        build_act<<<dim3(9, NTOK), 128, 0, stream>>>(hbuf, D_FF, regionA, ck * KCHUNK, K1);
        if (useZ) {
            if (ck == 0)
                gemm256<0><<<dim3(4, 16, 4), 512, 0, stream>>>(
                    regionA, KCHUNK, regionB + (size_t)ck * KCHUNK, K2,
                    zbuf, D_MODEL, 36, ZS, nullptr);
            else
                gemm256<2><<<dim3(4, 16, 4), 512, 0, stream>>>(
                    regionA, KCHUNK, regionB + (size_t)ck * KCHUNK, K2,
                    zbuf, D_MODEL, 36, ZS, nullptr);
        } else {
            gemm256<1><<<dim3(4, 16, 4), 512, 0, stream>>>(
                regionA, KCHUNK, regionB + (size_t)ck * KCHUNK, K2,
                out, D_MODEL, 36, ZS, nullptr);
        }
    }
    if (useZ)
        reduce4<<<(int)(ZS / 4 / 256), 256, 0, stream>>>(
            zbuf, out, (int)(ZS / 4), (int)(ZS / 4));
}